// Round 14
// baseline (439.441 us; speedup 1.0000x reference)
//
#include <hip/hip_runtime.h>
#include <hip/hip_fp16.h>
#include <math.h>

#define NN 50000
#define EE 800000
#define FIN 128
#define NH 5
#define HC 160
#define NG 64
#define CH2 32        // fast-path max items per node (deg <= 31), 16-lane groups
#define NB 160        // sort blocks
#define EPB 5000      // edges per sort block (NB*EPB == EE)
#define NW 12500      // packed histogram words (4 byte-bins per word)
#define ALS8 8        // padded stride for al_s (float4 + float loads)
#define LOG2E 1.4426950408889634f
#define WPAD 168      // w_sh group stride (160 + 8: bank-offset 8 per group)
#define IPAD 40       // ioff group stride (32 + 8)

typedef _Float16 f16x8 __attribute__((ext_vector_type(8)));
typedef _Float16 f16x4 __attribute__((ext_vector_type(4)));
typedef float f32x4 __attribute__((ext_vector_type(4)));

__device__ __forceinline__ float lrelu(float x, float s) { return x >= 0.f ? x : s * x; }

// unpack 4 consecutive fp16 (8B) to float4
__device__ __forceinline__ float4 h8_to_f4(uint2 u) {
    __half2 a = *reinterpret_cast<__half2*>(&u.x);
    __half2 b = *reinterpret_cast<__half2*>(&u.y);
    float2 fa = __half22float2(a), fb = __half22float2(b);
    return make_float4(fa.x, fa.y, fb.x, fb.y);
}

// ---------------- psum zero + per-graph node counts + per-layer s[h] + dbin zero
__global__ void prep_kernel(const int* __restrict__ batch, float* psum, int* gcnt,
                            const float* we1, const float* ae1,
                            const float* we2, const float* ae2, float* s_out,
                            int* dbin) {
    int i = blockIdx.x * 256 + threadIdx.x;
    if (i < NG * HC) psum[i] = 0.f;
    if (i < 256) dbin[i] = 0;
    if (i < NG) {
        int lo = 0, hi = NN;
        while (lo < hi) { int m = (lo + hi) >> 1; if (batch[m] < i) lo = m + 1; else hi = m; }
        int s = lo;
        lo = 0; hi = NN;
        int g1 = i + 1;
        while (lo < hi) { int m = (lo + hi) >> 1; if (batch[m] < g1) lo = m + 1; else hi = m; }
        gcnt[i] = lo - s;
    }
    if (i < 10) {
        const float* we = (i < 5) ? we1 : we2;
        const float* ae = (i < 5) ? ae1 : ae2;
        int h = i % 5;
        float s = 0.f;
        for (int c = 0; c < 32; c++) s += we[h * 32 + c] * ae[h * 32 + c];
        s_out[i] = s * LOG2E;          // exp2-domain
    }
}

// ---------------- W -> W^T fp16 (B-operands for MFMA): wt[c][k] = W[k][c]
__global__ void prepw_kernel(const float* __restrict__ w1, const float* __restrict__ w2,
                             const float* __restrict__ mw,
                             __half* wt1, __half* wt2, __half* wt3) {
    int i = blockIdx.x * 256 + threadIdx.x;
    if (i < 160 * 128) {
        int c = i >> 7, k = i & 127;
        wt1[i] = __float2half(w1[k * HC + c]);
    }
    if (i < 160 * 160) {
        int c = i / 160, k = i - c * 160;
        wt2[i] = __float2half(w2[k * HC + c]);
        wt3[i] = __float2half(mw[k * HC + c]);
    }
}

// ---------------- per-block LDS histogram of dst (byte-packed, no global atomics)
__global__ __launch_bounds__(256) void hist_kernel(const int* __restrict__ ei,
                                                   unsigned* __restrict__ hist_g) {
    __shared__ unsigned lh[NW];
    int b = blockIdx.x, tid = threadIdx.x;
    for (int w = tid; w < NW; w += 256) lh[w] = 0;
    __syncthreads();
    const int* dstp = ei + EE + b * EPB;
    for (int i = tid; i < EPB; i += 256) {
        int d = dstp[i];
        atomicAdd(&lh[d >> 2], 1u << ((d & 3) * 8));
    }
    __syncthreads();
    unsigned* outp = hist_g + (size_t)b * NW;
    for (int w = tid; w < NW; w += 256) outp[w] = lh[w];
}

// ---------------- column scan over blocks: per-(block,bin) base + total deg
//                  + 256-bin degree histogram (descending-sort schedule)
__global__ void sscan_kernel(const unsigned* __restrict__ hist_g,
                             unsigned short* __restrict__ base_g, int* __restrict__ deg,
                             int* __restrict__ dbin) {
    __shared__ int lbin[256];
    int tid = threadIdx.x;
    int w = blockIdx.x * 256 + tid;
    lbin[tid] = 0;
    __syncthreads();
    if (w < NW) {
        unsigned r0 = 0, r1 = 0, r2 = 0, r3 = 0;
        for (int b = 0; b < NB; b++) {
            unsigned x = hist_g[(size_t)b * NW + w];
            uint2 st;
            st.x = r0 | (r1 << 16);
            st.y = r2 | (r3 << 16);
            *reinterpret_cast<uint2*>(&base_g[(size_t)b * NN + 4 * w]) = st;
            r0 += x & 0xffu; r1 += (x >> 8) & 0xffu; r2 += (x >> 16) & 0xffu; r3 += (x >> 24) & 0xffu;
        }
        uint4 dv; dv.x = r0; dv.y = r1; dv.z = r2; dv.w = r3;
        *reinterpret_cast<uint4*>(&deg[4 * w]) = dv;
        atomicAdd(&lbin[255 - (int)(r0 > 255u ? 255u : r0)], 1);
        atomicAdd(&lbin[255 - (int)(r1 > 255u ? 255u : r1)], 1);
        atomicAdd(&lbin[255 - (int)(r2 > 255u ? 255u : r2)], 1);
        atomicAdd(&lbin[255 - (int)(r3 > 255u ? 255u : r3)], 1);
    }
    __syncthreads();
    if (lbin[tid]) atomicAdd(&dbin[tid], lbin[tid]);
}

// ------------------------------------------------------- 3-phase parallel scan
__global__ void scan1_kernel(const int* __restrict__ deg, int* bsum) {
    __shared__ int ws[4];
    int tid = threadIdx.x, lane = tid & 63, wid = tid >> 6;
    int i = blockIdx.x * 256 + tid;
    int v = (i < NN) ? deg[i] : 0;
    for (int o = 32; o >= 1; o >>= 1) v += __shfl_down(v, o, 64);
    if (lane == 0) ws[wid] = v;
    __syncthreads();
    if (tid == 0) bsum[blockIdx.x] = ws[0] + ws[1] + ws[2] + ws[3];
}

// block-sum prefix + 256-bin degree-histogram exclusive prefix (dpos)
__global__ void scan2_kernel(int* bsum, int* boff, const int* __restrict__ dbin,
                             int* __restrict__ dpos) {
    __shared__ int ws[4];
    int tid = threadIdx.x, lane = tid & 63, wid = tid >> 6;
    int v = (tid < 196) ? bsum[tid] : 0;
    int x = v;
    for (int o = 1; o < 64; o <<= 1) {
        int t = __shfl_up(x, o, 64);
        if (lane >= o) x += t;
    }
    if (lane == 63) ws[wid] = x;
    __syncthreads();
    if (tid == 0) {
        int acc = 0;
        for (int w = 0; w < 4; w++) { int t = ws[w]; ws[w] = acc; acc += t; }
    }
    __syncthreads();
    if (tid < 196) boff[tid] = x + ws[wid] - v;
    // ---- phase 2: degree-bin exclusive prefix (reuse ws after barrier)
    __syncthreads();
    int bv = dbin[tid];
    int bx = bv;
    for (int o = 1; o < 64; o <<= 1) {
        int t = __shfl_up(bx, o, 64);
        if (lane >= o) bx += t;
    }
    if (lane == 63) ws[wid] = bx;
    __syncthreads();
    if (tid == 0) {
        int acc = 0;
        for (int w = 0; w < 4; w++) { int t = ws[w]; ws[w] = acc; acc += t; }
    }
    __syncthreads();
    dpos[tid] = bx + ws[wid] - bv;
}

// scan3: node-offset scatter + LDS-aggregated counting-sort permutation
__global__ void scan3_kernel(const int* __restrict__ deg, const int* __restrict__ boff,
                             int* off, int* __restrict__ dpos, int* __restrict__ perm) {
    __shared__ int ws[4];
    __shared__ int lbin[256];    // per-block bin counts (LDS atomics)
    __shared__ int lbase[256];   // per-block reserved global base per bin
    int tid = threadIdx.x, lane = tid & 63, wid = tid >> 6;
    int i = blockIdx.x * 256 + tid;
    int v = (i < NN) ? deg[i] : 0;
    lbin[tid] = 0;
    int x = v;
    for (int o = 1; o < 64; o <<= 1) {
        int t = __shfl_up(x, o, 64);
        if (lane >= o) x += t;
    }
    if (lane == 63) ws[wid] = x;
    __syncthreads();
    if (tid == 0) {
        int acc = 0;
        for (int w = 0; w < 4; w++) { int t = ws[w]; ws[w] = acc; acc += t; }
    }
    __syncthreads();
    int incl = x + ws[wid] + boff[blockIdx.x];
    int bin = 255 - (v > 255 ? 255 : v);
    int rank = 0;
    if (i < NN) {
        off[i + 1] = incl;
        rank = atomicAdd(&lbin[bin], 1);     // fast LDS atomic
    }
    if (i == 0) off[0] = 0;
    __syncthreads();
    if (lbin[tid] > 0) lbase[tid] = atomicAdd(&dpos[tid], lbin[tid]);
    __syncthreads();
    if (i < NN) perm[lbase[bin] + rank] = i; // descending-degree schedule
}

// ---------------- rank via LDS + write packed edge record (no global atomics)
__global__ __launch_bounds__(256) void scatter_kernel(const int* __restrict__ ei,
                                                      const float* __restrict__ ea,
                                                      const unsigned short* __restrict__ base_g,
                                                      const int* __restrict__ soff,
                                                      uint4* __restrict__ erec) {
    __shared__ unsigned lc[NW];
    int b = blockIdx.x, tid = threadIdx.x;
    for (int w = tid; w < NW; w += 256) lc[w] = 0;
    __syncthreads();
    int e0 = b * EPB;
    const unsigned short* brow = base_g + (size_t)b * NN;
    for (int i = tid; i < EPB; i += 256) {
        int e = e0 + i;
        int d = ei[EE + e];
        int sh = (d & 3) * 8;
        unsigned old = atomicAdd(&lc[d >> 2], 1u << sh);
        int r = (int)((old >> sh) & 0xffu);
        int pos = soff[d] + (int)brow[d] + r;
        uint4 rec;
        rec.x = (unsigned)ei[e];
        rec.y = (unsigned)e;
        rec.z = __float_as_uint(ea[e]);
        rec.w = 0;
        erec[pos] = rec;
    }
}

// ---------------- MFMA GEMM: h = A @ W (K = 128 or 160), 32 rows x 160 cols per
//   128-thread block (2 waves).  Wave w: 32 rows x 80 cols = 2x5 mfma 16x16x32
//   tiles, fp16 inputs / fp32 accum.  W pre-transposed fp16 (Wt[c][k]).
//   LDS: Clds UNIONED into Bt's region (Bt dead after last MFMA) -> 16.6 KB
//   total -> 8 blocks/CU (was 28 KB / 5 blocks).
template <int K, typename AT>
__global__ __launch_bounds__(128, 4) void gemm_kernel(const AT* __restrict__ A,
                                                      const __half* __restrict__ Wt,
                                                      const float* __restrict__ a_s,
                                                      const float* __restrict__ a_d,
                                                      __half* __restrict__ out,
                                                      float* __restrict__ al_s,
                                                      float* __restrict__ al_d) {
    __shared__ __align__(16) char smem[16640];
    _Float16* Alds = (_Float16*)smem;                  // [32][40]  2560 B
    _Float16* Bt   = (_Float16*)(smem + 2560);         // [160][40] 12800 B
    _Float16* Clds = (_Float16*)(smem + 2560);         // epilogue: 2x[32][88] 11264 B (unions Bt)
    float* asld = (float*)(smem + 15360);              // 640 B
    float* adld = (float*)(smem + 16000);              // 640 B
    const int tid = threadIdx.x;
    const int w = tid >> 6, l = tid & 63;
    const int lr = l & 15, lq = l >> 4;
    const int base = blockIdx.x * 32;

    for (int i = tid; i < 160; i += 128) { asld[i] = a_s[i]; adld[i] = a_d[i]; }

    f32x4 acc[2][5];
#pragma unroll
    for (int mt = 0; mt < 2; mt++)
#pragma unroll
        for (int t = 0; t < 5; t++) acc[mt][t] = (f32x4){0.f, 0.f, 0.f, 0.f};

    for (int k0 = 0; k0 < K; k0 += 32) {
        __syncthreads();
        // ---- stage A (fp16, [row][k])
        if constexpr (sizeof(AT) == 4) {
            for (int f = tid; f < 256; f += 128) {
                int row = f >> 3, q = f & 7;
                float4 av = make_float4(0.f, 0.f, 0.f, 0.f);
                if (base + row < NN)
                    av = *reinterpret_cast<const float4*>(&A[(size_t)(base + row) * K + k0 + q * 4]);
                f16x4 hv = {(_Float16)av.x, (_Float16)av.y, (_Float16)av.z, (_Float16)av.w};
                *reinterpret_cast<f16x4*>(&Alds[row * 40 + q * 4]) = hv;
            }
        } else {
            int row = tid >> 2, q = tid & 3;
            uint4 v = make_uint4(0, 0, 0, 0);
            if (base + row < NN)
                v = *reinterpret_cast<const uint4*>(&A[(size_t)(base + row) * K + k0 + q * 8]);
            *reinterpret_cast<uint4*>(&Alds[row * 40 + q * 8]) = v;
        }
        // ---- stage B^T ([col][k]) from Wt fp16
        for (int f = tid; f < 640; f += 128) {
            int c = f >> 2, q = f & 3;
            uint4 v = *reinterpret_cast<const uint4*>(&Wt[(size_t)c * K + k0 + q * 8]);
            *reinterpret_cast<uint4*>(&Bt[c * 40 + q * 8]) = v;
        }
        __syncthreads();
        const f16x8 a0 = *reinterpret_cast<const f16x8*>(&Alds[lr * 40 + lq * 8]);
        const f16x8 a1 = *reinterpret_cast<const f16x8*>(&Alds[(16 + lr) * 40 + lq * 8]);
#pragma unroll
        for (int t = 0; t < 5; t++) {
            const f16x8 b = *reinterpret_cast<const f16x8*>(
                &Bt[((w * 5 + t) * 16 + lr) * 40 + lq * 8]);
            acc[0][t] = __builtin_amdgcn_mfma_f32_16x16x32_f16(a0, b, acc[0][t], 0, 0, 0);
            acc[1][t] = __builtin_amdgcn_mfma_f32_16x16x32_f16(a1, b, acc[1][t], 0, 0, 0);
        }
    }
    __syncthreads();   // all waves done reading Bt before Clds overwrites it
    // ---- C -> LDS (D layout: col = lane&15, row = (lane>>4)*4 + j)
    _Float16* Cw = Clds + w * (32 * 88);
#pragma unroll
    for (int mt = 0; mt < 2; mt++)
#pragma unroll
        for (int t = 0; t < 5; t++)
#pragma unroll
            for (int j = 0; j < 4; j++)
                Cw[(mt * 16 + lq * 4 + j) * 88 + t * 16 + lr] = (_Float16)acc[mt][t][j];
    __syncthreads();
    // ---- coalesced h store (fp16, 16B per thread-chunk)
    for (int i = l; i < 320; i += 64) {
        int row = i / 10, q = i - row * 10;
        if (base + row < NN) {
            uint4 v = *reinterpret_cast<const uint4*>(&Cw[row * 88 + q * 8]);
            *reinterpret_cast<uint4*>(&out[(size_t)(base + row) * HC + w * 80 + q * 8]) = v;
        }
    }
    // ---- att dots from Clds (both wave regions), exp2-domain
    for (int f = tid; f < 320; f += 128) {
        int row = f / 10, rem = f - row * 10;
        int h = rem >> 1, sd = rem & 1;
        if (base + row < NN) {
            const float* av = (sd ? adld : asld) + h * 32;
            float s = 0.f;
#pragma unroll
            for (int c = 0; c < 32; c++) {
                int col = h * 32 + c;
                int wv = col >= 80;
                s += (float)Clds[wv * (32 * 88) + row * 88 + (col - 80 * wv)] * av[c];
            }
            s *= LOG2E;
            if (sd) al_d[(size_t)(base + row) * NH + h] = s;
            else    al_s[(size_t)(base + row) * ALS8 + h] = s;
        }
    }
}

// ------------- per-node (16 LANES per node, 16 nodes per 256-block, degree-
//               sorted schedule via perm): segment softmax (exp2-domain) +
//               weighted fp16 gather + bias/lrelu/LN -> fp16 x_out.
//               Per-group LDS strides padded (+8 banks) so the 4 groups of a
//               wave never collide.  No barrier (wave-local LDS only).
__global__ __launch_bounds__(256, 8) void aggregate_kernel(
    const int* __restrict__ perm,
    const int* __restrict__ soff, const uint4* __restrict__ erec,
    const __half* __restrict__ hfeat, const float* __restrict__ als,
    const float* __restrict__ al_d, const float* __restrict__ s_e,
    const float* __restrict__ bias, const float* __restrict__ g_ln,
    const float* __restrict__ b_ln,
    float* __restrict__ alpha_out, __half* __restrict__ x_out) {
    const int tid = threadIdx.x;
    const int grp = tid >> 4;          // node group 0..15 in block
    const int sl = tid & 15;           // sub-lane within group
    const int n = perm[blockIdx.x * 16 + grp];
    __shared__ float w_sh_all[16][WPAD];
    __shared__ int ioff_all[16][IPAD];  // byte offsets into hfeat (src*HC*2)
    float* w_sh = w_sh_all[grp];
    int* ioff_sh = ioff_all[grp];

    const int s0 = soff[n];
    const int deg = soff[n + 1] - s0;
    const int items = deg + 1;

    float adr[NH], ser[NH];
#pragma unroll
    for (int h = 0; h < NH; h++) { adr[h] = al_d[n * NH + h]; ser[h] = s_e[h]; }

    const int cA = sl * 4, cB = 64 + sl * 4, cC = 128 + sl * 2;
    const int hA = sl >> 3, hB = 2 + (sl >> 3);       // hC = 4
    float4 accA = make_float4(0.f, 0.f, 0.f, 0.f);
    float4 accB = make_float4(0.f, 0.f, 0.f, 0.f);
    float2 accC = make_float2(0.f, 0.f);

    if (items <= CH2) {
        // ---- pass A: logits into registers (2 tiles x 5 heads), per-head max, ea sum
        float rw[2][NH];
        float lm[NH];
#pragma unroll
        for (int h = 0; h < NH; h++) lm[h] = -3.0e38f;
        float eas = 0.f;
        int myy[2];
#pragma unroll
        for (int t = 0; t < 2; t++) {
            if (deg > 16 * t) {                  // group-uniform guard
                int i = sl + 16 * t;
                if (i < deg) {
                    uint4 rec = erec[s0 + i];
                    int src = (int)rec.x;
                    float eav = __uint_as_float(rec.z);
                    ioff_sh[i] = src * (HC * 2);
                    myy[t] = (int)rec.y;
                    eas += eav;
                    const float* ap = als + (size_t)src * ALS8;
                    float4 a4 = *reinterpret_cast<const float4*>(ap);
                    float a5 = ap[4];
                    float asv[5] = {a4.x, a4.y, a4.z, a4.w, a5};
#pragma unroll
                    for (int h = 0; h < NH; h++) {
                        float r = lrelu(asv[h] + adr[h] + eav * ser[h], 0.2f);
                        rw[t][h] = r;
                        lm[h] = fmaxf(lm[h], r);
                    }
                }
            }
        }
        // ---- 16-lane butterfly: max per head, sum of edge attrs
#pragma unroll
        for (int o = 1; o < 16; o <<= 1) {
#pragma unroll
            for (int h = 0; h < NH; h++) lm[h] = fmaxf(lm[h], __shfl_xor(lm[h], o, 64));
            eas += __shfl_xor(eas, o, 64);
        }
        float emean = eas / fmaxf((float)deg, 1.f);
        float m[NH], rs[NH];
        {
            const float* ap = als + (size_t)n * ALS8;
            float4 a4 = *reinterpret_cast<const float4*>(ap);
            float a5 = ap[4];
            float asv[5] = {a4.x, a4.y, a4.z, a4.w, a5};
#pragma unroll
            for (int h = 0; h < NH; h++) {
                rs[h] = lrelu(asv[h] + adr[h] + emean * ser[h], 0.2f);
                m[h] = fmaxf(lm[h], rs[h]);
            }
        }
        // ---- pass B: exp2 in registers + sum
        float ls[NH] = {0.f, 0.f, 0.f, 0.f, 0.f};
#pragma unroll
        for (int t = 0; t < 2; t++) {
            if (items > 16 * t) {
                int i = sl + 16 * t;
                if (i < deg) {
#pragma unroll
                    for (int h = 0; h < NH; h++) {
                        float w = exp2f(rw[t][h] - m[h]);
                        rw[t][h] = w;
                        ls[h] += w;
                    }
                } else if (i == deg) {           // self-loop owner lane
                    ioff_sh[i] = n * (HC * 2);
#pragma unroll
                    for (int h = 0; h < NH; h++) {
                        float w = exp2f(rs[h] - m[h]);
                        rw[t][h] = w;
                        ls[h] += w;
                    }
                }
            }
        }
#pragma unroll
        for (int o = 1; o < 16; o <<= 1) {
#pragma unroll
            for (int h = 0; h < NH; h++) ls[h] += __shfl_xor(ls[h], o, 64);
        }
        float dinv[NH];
#pragma unroll
        for (int h = 0; h < NH; h++) dinv[h] = 1.f / ls[h];
        // ---- normalize: final weights -> LDS + alpha writeback
#pragma unroll
        for (int t = 0; t < 2; t++) {
            if (items > 16 * t) {
                int i = sl + 16 * t;
                if (i < items) {
                    int opos = (i < deg) ? myy[t] : (EE + n);
#pragma unroll
                    for (int h = 0; h < NH; h++) {
                        float w = rw[t][h] * dinv[h];
                        w_sh[i * NH + h] = w;
                        alpha_out[(size_t)opos * NH + h] = w;
                    }
                }
            }
        }
        // (no barrier: w_sh/ioff_sh written+read by this wave only)
        // ---- pass C: 4-deep pipelined fp16 gather, 10 channels per lane
        const char* hb = (const char*)hfeat;
        for (int i0 = 0; i0 < items; i0 += 4) {
            float wA[4], wB[4], wC[4];
            uint2 vA[4], vB[4];
            unsigned vC[4];
#pragma unroll
            for (int j = 0; j < 4; j++) {
                int i = i0 + j;
                bool ok = i < items;
                int ii = ok ? i : 0;
                const char* rp = hb + (size_t)(unsigned)ioff_sh[ii];
                wA[j] = ok ? w_sh[ii * NH + hA] : 0.f;
                wB[j] = ok ? w_sh[ii * NH + hB] : 0.f;
                wC[j] = ok ? w_sh[ii * NH + 4] : 0.f;
                vA[j] = *reinterpret_cast<const uint2*>(rp + cA * 2);
                vB[j] = *reinterpret_cast<const uint2*>(rp + cB * 2);
                vC[j] = *reinterpret_cast<const unsigned*>(rp + cC * 2);
            }
#pragma unroll
            for (int j = 0; j < 4; j++) {
                float4 fA = h8_to_f4(vA[j]);
                accA.x += wA[j] * fA.x; accA.y += wA[j] * fA.y;
                accA.z += wA[j] * fA.z; accA.w += wA[j] * fA.w;
                float4 fB = h8_to_f4(vB[j]);
                accB.x += wB[j] * fB.x; accB.y += wB[j] * fB.y;
                accB.z += wB[j] * fB.z; accB.w += wB[j] * fB.w;
                __half2 pC = *reinterpret_cast<__half2*>(&vC[j]);
                accC.x += wC[j] * __low2float(pC);
                accC.y += wC[j] * __high2float(pC);
            }
        }
    } else {
        // ---- slow path (deg >= CH2): 16-lane streaming recompute, no LDS
        float lm[NH];
#pragma unroll
        for (int h = 0; h < NH; h++) lm[h] = -3.0e38f;
        float eas = 0.f;
        for (int i = sl; i < deg; i += 16) {
            uint4 rec = erec[s0 + i];
            int src = (int)rec.x;
            float eav = __uint_as_float(rec.z);
            eas += eav;
            const float* ap = als + (size_t)src * ALS8;
            float4 a4 = *reinterpret_cast<const float4*>(ap);
            float a5 = ap[4];
            float asv[5] = {a4.x, a4.y, a4.z, a4.w, a5};
#pragma unroll
            for (int h = 0; h < NH; h++) {
                float r = lrelu(asv[h] + adr[h] + eav * ser[h], 0.2f);
                lm[h] = fmaxf(lm[h], r);
            }
        }
#pragma unroll
        for (int o = 1; o < 16; o <<= 1) {
#pragma unroll
            for (int h = 0; h < NH; h++) lm[h] = fmaxf(lm[h], __shfl_xor(lm[h], o, 64));
            eas += __shfl_xor(eas, o, 64);
        }
        float emean = eas / fmaxf((float)deg, 1.f);
        float m[NH], rs[NH];
        {
            const float* ap = als + (size_t)n * ALS8;
#pragma unroll
            for (int h = 0; h < NH; h++) {
                rs[h] = lrelu(ap[h] + adr[h] + emean * ser[h], 0.2f);
                m[h] = fmaxf(lm[h], rs[h]);
            }
        }
        float ls[NH] = {0.f, 0.f, 0.f, 0.f, 0.f};
        for (int i = sl; i < items; i += 16) {
            int src; float eav;
            if (i < deg) { uint4 rec = erec[s0 + i]; src = (int)rec.x; eav = __uint_as_float(rec.z); }
            else         { src = n; eav = emean; }
            const float* ap = als + (size_t)src * ALS8;
#pragma unroll
            for (int h = 0; h < NH; h++) {
                float r = lrelu(ap[h] + adr[h] + eav * ser[h], 0.2f);
                ls[h] += exp2f(r - m[h]);
            }
        }
#pragma unroll
        for (int o = 1; o < 16; o <<= 1) {
#pragma unroll
            for (int h = 0; h < NH; h++) ls[h] += __shfl_xor(ls[h], o, 64);
        }
        float dinv[NH];
#pragma unroll
        for (int h = 0; h < NH; h++) dinv[h] = 1.f / ls[h];
        for (int i = sl; i < items; i += 16) {
            int src; float eav; int opos;
            if (i < deg) { uint4 rec = erec[s0 + i]; src = (int)rec.x; eav = __uint_as_float(rec.z); opos = (int)rec.y; }
            else         { src = n; eav = emean; opos = EE + n; }
            const float* ap = als + (size_t)src * ALS8;
#pragma unroll
            for (int h = 0; h < NH; h++) {
                float r = lrelu(ap[h] + adr[h] + eav * ser[h], 0.2f);
                alpha_out[(size_t)opos * NH + h] = exp2f(r - m[h]) * dinv[h];
            }
        }
        // serial gather over items; 16 lanes cover the 160 channels
        for (int i = 0; i < items; i++) {
            int src; float eav;
            if (i < deg) { uint4 rec = erec[s0 + i]; src = (int)rec.x; eav = __uint_as_float(rec.z); }
            else         { src = n; eav = emean; }
            const float* ap = als + (size_t)src * ALS8;
            float wAv = exp2f(lrelu(ap[hA] + adr[hA] + eav * ser[hA], 0.2f) - m[hA]) * dinv[hA];
            float wBv = exp2f(lrelu(ap[hB] + adr[hB] + eav * ser[hB], 0.2f) - m[hB]) * dinv[hB];
            float wCv = exp2f(lrelu(ap[4] + adr[4] + eav * ser[4], 0.2f) - m[4]) * dinv[4];
            const char* rp = (const char*)hfeat + (size_t)src * (HC * 2);
            uint2 vA = *reinterpret_cast<const uint2*>(rp + cA * 2);
            uint2 vB = *reinterpret_cast<const uint2*>(rp + cB * 2);
            unsigned vC = *reinterpret_cast<const unsigned*>(rp + cC * 2);
            float4 fA = h8_to_f4(vA);
            accA.x += wAv * fA.x; accA.y += wAv * fA.y;
            accA.z += wAv * fA.z; accA.w += wAv * fA.w;
            float4 fB = h8_to_f4(vB);
            accB.x += wBv * fB.x; accB.y += wBv * fB.y;
            accB.z += wBv * fB.z; accB.w += wBv * fB.w;
            __half2 pC = *reinterpret_cast<__half2*>(&vC);
            accC.x += wCv * __low2float(pC);
            accC.y += wCv * __high2float(pC);
        }
    }

    // ---- bias + lrelu + fused LayerNorm across 160 channels (16-lane butterfly)
    const float4 bA = *reinterpret_cast<const float4*>(&bias[cA]);
    const float4 bB = *reinterpret_cast<const float4*>(&bias[cB]);
    const float2 bC = *reinterpret_cast<const float2*>(&bias[cC]);
    float v0 = lrelu(accA.x + bA.x, 0.01f);
    float v1 = lrelu(accA.y + bA.y, 0.01f);
    float v2 = lrelu(accA.z + bA.z, 0.01f);
    float v3 = lrelu(accA.w + bA.w, 0.01f);
    float v4 = lrelu(accB.x + bB.x, 0.01f);
    float v5 = lrelu(accB.y + bB.y, 0.01f);
    float v6 = lrelu(accB.z + bB.z, 0.01f);
    float v7 = lrelu(accB.w + bB.w, 0.01f);
    float v8 = lrelu(accC.x + bC.x, 0.01f);
    float v9 = lrelu(accC.y + bC.y, 0.01f);
    float p1 = v0 + v1 + v2 + v3 + v4 + v5 + v6 + v7 + v8 + v9;
    float p2 = v0 * v0 + v1 * v1 + v2 * v2 + v3 * v3 + v4 * v4 +
               v5 * v5 + v6 * v6 + v7 * v7 + v8 * v8 + v9 * v9;
#pragma unroll
    for (int o = 1; o < 16; o <<= 1) {
        p1 += __shfl_xor(p1, o, 64);
        p2 += __shfl_xor(p2, o, 64);
    }
    float mean = p1 * (1.f / (float)HC);
    float var = p2 * (1.f / (float)HC) - mean * mean;
    float rstd = rsqrtf(var + 1e-5f);
    const float4 gA = *reinterpret_cast<const float4*>(&g_ln[cA]);
    const float4 gB = *reinterpret_cast<const float4*>(&g_ln[cB]);
    const float2 gC = *reinterpret_cast<const float2*>(&g_ln[cC]);
    const float4 tA = *reinterpret_cast<const float4*>(&b_ln[cA]);
    const float4 tB = *reinterpret_cast<const float4*>(&b_ln[cB]);
    const float2 tC = *reinterpret_cast<const float2*>(&b_ln[cC]);
    float o0 = (v0 - mean) * rstd * gA.x + tA.x;
    float o1 = (v1 - mean) * rstd * gA.y + tA.y;
    float o2 = (v2 - mean) * rstd * gA.z + tA.z;
    float o3 = (v3 - mean) * rstd * gA.w + tA.w;
    float o4 = (v4 - mean) * rstd * gB.x + tB.x;
    float o5 = (v5 - mean) * rstd * gB.y + tB.y;
    float o6 = (v6 - mean) * rstd * gB.z + tB.z;
    float o7 = (v7 - mean) * rstd * gB.w + tB.w;
    float o8 = (v8 - mean) * rstd * gC.x + tC.x;
    float o9 = (v9 - mean) * rstd * gC.y + tC.y;
    {
        __half2 hA01 = __floats2half2_rn(o0, o1);
        __half2 hA23 = __floats2half2_rn(o2, o3);
        uint2 stA;
        stA.x = *reinterpret_cast<unsigned*>(&hA01);
        stA.y = *reinterpret_cast<unsigned*>(&hA23);
        *reinterpret_cast<uint2*>(&x_out[(size_t)n * HC + cA]) = stA;
        __half2 hB01 = __floats2half2_rn(o4, o5);
        __half2 hB23 = __floats2half2_rn(o6, o7);
        uint2 stB;
        stB.x = *reinterpret_cast<unsigned*>(&hB01);
        stB.y = *reinterpret_cast<unsigned*>(&hB23);
        *reinterpret_cast<uint2*>(&x_out[(size_t)n * HC + cB]) = stB;
        __half2 hC = __floats2half2_rn(o8, o9);
        *reinterpret_cast<unsigned*>(&x_out[(size_t)n * HC + cC]) =
            *reinterpret_cast<unsigned*>(&hC);
    }
}

// -------- x3 = lrelu(x2 @ mw + mb) (MFMA, x2 fp16); direct fp32 store + pooled
__global__ __launch_bounds__(128, 4) void gemm3_kernel(const __half* __restrict__ A,
                                                       const __half* __restrict__ Wt,
                                                       const float* __restrict__ bias,
                                                       const int* __restrict__ batch,
                                                       float* __restrict__ x3,
                                                       float* __restrict__ psum) {
    __shared__ __align__(16) _Float16 Alds[32 * 40];
    __shared__ __align__(16) _Float16 Bt[160 * 40];
    __shared__ int bt[32];
    const int tid = threadIdx.x;
    const int w = tid >> 6, l = tid & 63;
    const int lr = l & 15, lq = l >> 4;
    const int base = blockIdx.x * 32;

    if (tid < 32) bt[tid] = batch[(base + tid < NN) ? (base + tid) : (NN - 1)];

    f32x4 acc[2][5];
#pragma unroll
    for (int mt = 0; mt < 2; mt++)
#pragma unroll
        for (int t = 0; t < 5; t++) acc[mt][t] = (f32x4){0.f, 0.f, 0.f, 0.f};

    for (int k0 = 0; k0 < HC; k0 += 32) {
        __syncthreads();
        {
            int row = tid >> 2, q = tid & 3;
            uint4 v = make_uint4(0, 0, 0, 0);
            if (base + row < NN)
                v = *reinterpret_cast<const uint4*>(&A[(size_t)(base + row) * HC + k0 + q * 8]);
            *reinterpret_cast<uint4*>(&Alds[row * 40 + q * 8]) = v;
        }
        for (int f = tid; f < 640; f += 128) {
            int c = f >> 2, q = f & 3;
            uint4 v = *reinterpret_cast<const uint4*>(&Wt[(size_t)c * HC + k0 + q * 8]);
            *reinterpret_cast<uint4*>(&Bt[c * 40 + q * 8]) = v;
        }
        __syncthreads();
        const f16x8 a0 = *reinterpret_cast<const f16x8*>(&Alds[lr * 40 + lq * 8]);
        const f16x8 a1 = *reinterpret_cast<const f16x8*>(&Alds[(16 + lr) * 40 + lq * 8]);
#pragma unroll
        for (int t = 0; t < 5; t++) {
            const f16x8 b = *reinterpret_cast<const f16x8*>(
                &Bt[((w * 5 + t) * 16 + lr) * 40 + lq * 8]);
            acc[0][t] = __builtin_amdgcn_mfma_f32_16x16x32_f16(a0, b, acc[0][t], 0, 0, 0);
            acc[1][t] = __builtin_amdgcn_mfma_f32_16x16x32_f16(a1, b, acc[1][t], 0, 0, 0);
        }
    }
    // ---- bias + lrelu, direct x3 store (quarter-coalesced), run-length pooled
#pragma unroll
    for (int t = 0; t < 5; t++) {
        int col = w * 80 + t * 16 + lr;
        float bj = bias[col];
        float run = 0.f;
        int g = bt[lq * 4];
#pragma unroll
        for (int mt = 0; mt < 2; mt++)
#pragma unroll
            for (int j = 0; j < 4; j++) {
                int row = mt * 16 + lq * 4 + j;
                bool ok = base + row < NN;
                float vv = lrelu(acc[mt][t][j] + bj, 0.01f);
                if (ok) x3[(size_t)(base + row) * HC + col] = vv;
                int gb = bt[row];
                if (gb != g) { atomicAdd(&psum[g * HC + col], run); run = 0.f; g = gb; }
                if (ok) run += vv;
            }
        atomicAdd(&psum[g * HC + col], run);
    }
}

__global__ void pooldiv_kernel(const float* __restrict__ psum, const int* __restrict__ gcnt,
                               float* pooled_out) {
    int i = blockIdx.x * 256 + threadIdx.x;
    if (i < NG * HC) pooled_out[i] = psum[i] / fmaxf((float)gcnt[i / HC], 1.f);
}

// ---------------------------------------------------------------------- launch
extern "C" void kernel_launch(void* const* d_in, const int* in_sizes, int n_in,
                              void* d_out, int out_size, void* d_ws, size_t ws_size,
                              hipStream_t stream) {
    const float* x    = (const float*)d_in[0];
    const int*   ei   = (const int*)d_in[1];
    const float* ea   = (const float*)d_in[2];
    const int*   batch= (const int*)d_in[3];
    const float* w1   = (const float*)d_in[4];
    const float* we1  = (const float*)d_in[5];
    const float* as1  = (const float*)d_in[6];
    const float* ad1  = (const float*)d_in[7];
    const float* ae1  = (const float*)d_in[8];
    const float* b1   = (const float*)d_in[9];
    const float* w2   = (const float*)d_in[10];
    const float* we2  = (const float*)d_in[11];
    const float* as2  = (const float*)d_in[12];
    const float* ad2  = (const float*)d_in[13];
    const float* ae2  = (const float*)d_in[14];
    const float* b2   = (const float*)d_in[15];
    const float* ln1g = (const float*)d_in[16];
    const float* ln1b = (const float*)d_in[17];
    const float* ln2g = (const float*)d_in[18];
    const float* ln2b = (const float*)d_in[19];
    const float* mw   = (const float*)d_in[20];
    const float* mb   = (const float*)d_in[21];

    float* out = (float*)d_out;
    float* pooled_out = out + (size_t)NN * HC;
    float* a1 = pooled_out + NG * HC;
    float* a2 = a1 + (size_t)(EE + NN) * NH;

    char* wp = (char*)d_ws;
    auto alloc = [&](size_t bytes) {
        void* p = (void*)wp;
        wp += (bytes + 255) & ~(size_t)255;
        return p;
    };
    // 32MB region, triple-overlaid in time:
    //   [0..8)   hist_g   (dead after sscan)     -> [0..16)  h fp16
    //   [8..24)  base_g   (dead after scatter)   -> [16..32) x12h fp16
    char* region = (char*)alloc(32 * 1024 * 1024);
    __half* hbuf = (__half*)region;                               // 16 MB fp16 h
    __half* x12h = (__half*)(region + 16 * 1024 * 1024);          // 16 MB fp16 x1/x2
    unsigned*       hist_g = (unsigned*)region;                   // 8 MB
    unsigned short* base_g = (unsigned short*)(region + 8 * 1024 * 1024); // 16 MB
    uint4* erec  = (uint4*)alloc((size_t)EE * 16);       // 12.8 MB
    float* als   = (float*)alloc((size_t)NN * ALS8 * 4); // padded al_s
    float* ald   = (float*)alloc((size_t)NN * NH * 4);
    int*   deg   = (int*)alloc((size_t)NN * 4);
    int*   soff  = (int*)alloc((size_t)(NN + 1) * 4);
    float* sbuf  = (float*)alloc(64);
    float* psum  = (float*)alloc((size_t)NG * HC * 4);
    int*   gcnt  = (int*)alloc((size_t)NG * 4);
    int*   bsum  = (int*)alloc(256 * 4);
    int*   boff  = (int*)alloc(256 * 4);
    int*   dbin  = (int*)alloc(256 * 4);
    int*   dpos  = (int*)alloc(256 * 4);
    int*   perm  = (int*)alloc((size_t)NN * 4);
    __half* wt1  = (__half*)alloc((size_t)160 * 128 * 2);  // W^T fp16 per layer
    __half* wt2  = (__half*)alloc((size_t)160 * 160 * 2);
    __half* wt3  = (__half*)alloc((size_t)160 * 160 * 2);

    prep_kernel<<<40, 256, 0, stream>>>(batch, psum, gcnt, we1, ae1, we2, ae2, sbuf, dbin);
    prepw_kernel<<<100, 256, 0, stream>>>(w1, w2, mw, wt1, wt2, wt3);
    hist_kernel<<<NB, 256, 0, stream>>>(ei, hist_g);
    sscan_kernel<<<49, 256, 0, stream>>>(hist_g, base_g, deg, dbin);
    scan1_kernel<<<196, 256, 0, stream>>>(deg, bsum);
    scan2_kernel<<<1, 256, 0, stream>>>(bsum, boff, dbin, dpos);
    scan3_kernel<<<196, 256, 0, stream>>>(deg, boff, soff, dpos, perm);
    scatter_kernel<<<NB, 256, 0, stream>>>(ei, ea, base_g, soff, erec);

    const int GB = (NN + 31) / 32;   // 1563 gemm blocks

    gemm_kernel<128, float><<<GB, 128, 0, stream>>>(x, wt1, as1, ad1, hbuf, als, ald);
    aggregate_kernel<<<3125, 256, 0, stream>>>(perm, soff, erec, hbuf, als, ald,
                                               sbuf, b1, ln1g, ln1b, a1, x12h);

    gemm_kernel<160, __half><<<GB, 128, 0, stream>>>(x12h, wt2, as2, ad2, hbuf, als, ald);
    aggregate_kernel<<<3125, 256, 0, stream>>>(perm, soff, erec, hbuf, als, ald,
                                               sbuf + 5, b2, ln2g, ln2b, a2, x12h);

    gemm3_kernel<<<GB, 128, 0, stream>>>(x12h, wt3, mb, batch, out, psum);
    pooldiv_kernel<<<40, 256, 0, stream>>>(psum, gcnt, pooled_out);
}

// Round 15
// 415.363 us; speedup vs baseline: 1.0580x; 1.0580x over previous
//
#include <hip/hip_runtime.h>
#include <hip/hip_fp16.h>
#include <math.h>

#define NN 50000
#define EE 800000
#define FIN 128
#define NH 5
#define HC 160
#define NG 64
#define CH2 32        // fast-path max items per node (deg <= 31), 16-lane groups
#define NB 160        // sort blocks
#define EPB 5000      // edges per sort block (NB*EPB == EE)
#define NW 12500      // packed histogram words (4 byte-bins per word)
#define ALS8 8        // padded stride for al_s (float4 + float loads)
#define LOG2E 1.4426950408889634f
#define WPAD 168      // w_sh group stride (160 + 8: bank-offset 8 per group)
#define IPAD 40       // ioff group stride (32 + 8)

typedef _Float16 f16x8 __attribute__((ext_vector_type(8)));
typedef _Float16 f16x4 __attribute__((ext_vector_type(4)));
typedef float f32x4 __attribute__((ext_vector_type(4)));

__device__ __forceinline__ float lrelu(float x, float s) { return x >= 0.f ? x : s * x; }

// unpack 4 consecutive fp16 (8B) to float4
__device__ __forceinline__ float4 h8_to_f4(uint2 u) {
    __half2 a = *reinterpret_cast<__half2*>(&u.x);
    __half2 b = *reinterpret_cast<__half2*>(&u.y);
    float2 fa = __half22float2(a), fb = __half22float2(b);
    return make_float4(fa.x, fa.y, fb.x, fb.y);
}

// ---------------- FUSED prep + prepw + hist (mutually independent):
//   blocks [0,40): psum zero + gcnt + s[h] + dbin zero
//   blocks [40,140): W -> W^T fp16
//   blocks [140,300): per-block LDS histogram of dst
__global__ __launch_bounds__(256) void prep_fused_kernel(
    const int* __restrict__ batch, float* psum, int* gcnt,
    const float* we1, const float* ae1, const float* we2, const float* ae2,
    float* s_out, int* dbin,
    const float* __restrict__ w1, const float* __restrict__ w2,
    const float* __restrict__ mw, __half* wt1, __half* wt2, __half* wt3,
    const int* __restrict__ ei, unsigned* __restrict__ hist_g) {
    __shared__ unsigned lh[NW];
    const int b = blockIdx.x, tid = threadIdx.x;
    if (b < 40) {
        int i = b * 256 + tid;
        if (i < NG * HC) psum[i] = 0.f;
        if (i < 256) dbin[i] = 0;
        if (i < NG) {
            int lo = 0, hi = NN;
            while (lo < hi) { int m = (lo + hi) >> 1; if (batch[m] < i) lo = m + 1; else hi = m; }
            int s = lo;
            lo = 0; hi = NN;
            int g1 = i + 1;
            while (lo < hi) { int m = (lo + hi) >> 1; if (batch[m] < g1) lo = m + 1; else hi = m; }
            gcnt[i] = lo - s;
        }
        if (i < 10) {
            const float* we = (i < 5) ? we1 : we2;
            const float* ae = (i < 5) ? ae1 : ae2;
            int h = i % 5;
            float s = 0.f;
            for (int c = 0; c < 32; c++) s += we[h * 32 + c] * ae[h * 32 + c];
            s_out[i] = s * LOG2E;          // exp2-domain
        }
    } else if (b < 140) {
        int i = (b - 40) * 256 + tid;
        if (i < 160 * 128) {
            int c = i >> 7, k = i & 127;
            wt1[i] = __float2half(w1[k * HC + c]);
        }
        if (i < 160 * 160) {
            int c = i / 160, k = i - c * 160;
            wt2[i] = __float2half(w2[k * HC + c]);
            wt3[i] = __float2half(mw[k * HC + c]);
        }
    } else {
        int bb = b - 140;
        for (int w = tid; w < NW; w += 256) lh[w] = 0;
        __syncthreads();
        const int* dstp = ei + EE + bb * EPB;
        for (int i = tid; i < EPB; i += 256) {
            int d = dstp[i];
            atomicAdd(&lh[d >> 2], 1u << ((d & 3) * 8));
        }
        __syncthreads();
        unsigned* outp = hist_g + (size_t)bb * NW;
        for (int w = tid; w < NW; w += 256) outp[w] = lh[w];
    }
}

// ---------------- MFMA GEMM body: h = A @ W (K = 128 or 160), 32 rows x 160
//   cols per 128 threads (2 waves).  Wave w: 32 rows x 80 cols = 2x5 mfma
//   16x16x32 tiles, fp16 inputs / fp32 accum.  W pre-transposed fp16.
//   smem must be >= 16640 B.
template <int K, typename AT>
__device__ __forceinline__ void gemm_body(int bidx, int tid, char* smem,
                                          const AT* __restrict__ A,
                                          const __half* __restrict__ Wt,
                                          const float* __restrict__ a_s,
                                          const float* __restrict__ a_d,
                                          __half* __restrict__ out,
                                          float* __restrict__ al_s,
                                          float* __restrict__ al_d) {
    _Float16* Alds = (_Float16*)smem;                  // [32][40]  2560 B
    _Float16* Bt   = (_Float16*)(smem + 2560);         // [160][40] 12800 B
    _Float16* Clds = (_Float16*)(smem + 2560);         // epilogue: 2x[32][88] (unions Bt)
    float* asld = (float*)(smem + 15360);              // 640 B
    float* adld = (float*)(smem + 16000);              // 640 B
    const int w = tid >> 6, l = tid & 63;
    const int lr = l & 15, lq = l >> 4;
    const int base = bidx * 32;

    for (int i = tid; i < 160; i += 128) { asld[i] = a_s[i]; adld[i] = a_d[i]; }

    f32x4 acc[2][5];
#pragma unroll
    for (int mt = 0; mt < 2; mt++)
#pragma unroll
        for (int t = 0; t < 5; t++) acc[mt][t] = (f32x4){0.f, 0.f, 0.f, 0.f};

    for (int k0 = 0; k0 < K; k0 += 32) {
        __syncthreads();
        // ---- stage A (fp16, [row][k])
        if constexpr (sizeof(AT) == 4) {
            for (int f = tid; f < 256; f += 128) {
                int row = f >> 3, q = f & 7;
                float4 av = make_float4(0.f, 0.f, 0.f, 0.f);
                if (base + row < NN)
                    av = *reinterpret_cast<const float4*>(&A[(size_t)(base + row) * K + k0 + q * 4]);
                f16x4 hv = {(_Float16)av.x, (_Float16)av.y, (_Float16)av.z, (_Float16)av.w};
                *reinterpret_cast<f16x4*>(&Alds[row * 40 + q * 4]) = hv;
            }
        } else {
            int row = tid >> 2, q = tid & 3;
            uint4 v = make_uint4(0, 0, 0, 0);
            if (base + row < NN)
                v = *reinterpret_cast<const uint4*>(&A[(size_t)(base + row) * K + k0 + q * 8]);
            *reinterpret_cast<uint4*>(&Alds[row * 40 + q * 8]) = v;
        }
        // ---- stage B^T ([col][k]) from Wt fp16
        for (int f = tid; f < 640; f += 128) {
            int c = f >> 2, q = f & 3;
            uint4 v = *reinterpret_cast<const uint4*>(&Wt[(size_t)c * K + k0 + q * 8]);
            *reinterpret_cast<uint4*>(&Bt[c * 40 + q * 8]) = v;
        }
        __syncthreads();
        const f16x8 a0 = *reinterpret_cast<const f16x8*>(&Alds[lr * 40 + lq * 8]);
        const f16x8 a1 = *reinterpret_cast<const f16x8*>(&Alds[(16 + lr) * 40 + lq * 8]);
#pragma unroll
        for (int t = 0; t < 5; t++) {
            const f16x8 b = *reinterpret_cast<const f16x8*>(
                &Bt[((w * 5 + t) * 16 + lr) * 40 + lq * 8]);
            acc[0][t] = __builtin_amdgcn_mfma_f32_16x16x32_f16(a0, b, acc[0][t], 0, 0, 0);
            acc[1][t] = __builtin_amdgcn_mfma_f32_16x16x32_f16(a1, b, acc[1][t], 0, 0, 0);
        }
    }
    __syncthreads();   // all waves done reading Bt before Clds overwrites it
    // ---- C -> LDS (D layout: col = lane&15, row = (lane>>4)*4 + j)
    _Float16* Cw = Clds + w * (32 * 88);
#pragma unroll
    for (int mt = 0; mt < 2; mt++)
#pragma unroll
        for (int t = 0; t < 5; t++)
#pragma unroll
            for (int j = 0; j < 4; j++)
                Cw[(mt * 16 + lq * 4 + j) * 88 + t * 16 + lr] = (_Float16)acc[mt][t][j];
    __syncthreads();
    // ---- coalesced h store (fp16, 16B per thread-chunk)
    for (int i = l; i < 320; i += 64) {
        int row = i / 10, q = i - row * 10;
        if (base + row < NN) {
            uint4 v = *reinterpret_cast<const uint4*>(&Cw[row * 88 + q * 8]);
            *reinterpret_cast<uint4*>(&out[(size_t)(base + row) * HC + w * 80 + q * 8]) = v;
        }
    }
    // ---- att dots from Clds (both wave regions), exp2-domain
    for (int f = tid; f < 320; f += 128) {
        int row = f / 10, rem = f - row * 10;
        int h = rem >> 1, sd = rem & 1;
        if (base + row < NN) {
            const float* av = (sd ? adld : asld) + h * 32;
            float s = 0.f;
#pragma unroll
            for (int c = 0; c < 32; c++) {
                int col = h * 32 + c;
                int wv = col >= 80;
                s += (float)Clds[wv * (32 * 88) + row * 88 + (col - 80 * wv)] * av[c];
            }
            s *= LOG2E;
            if (sd) al_d[(size_t)(base + row) * NH + h] = s;
            else    al_s[(size_t)(base + row) * ALS8 + h] = s;
        }
    }
}

// ---------------- FUSED sscan + gemm1 (independent after prep_fused):
//   blocks [0,49): column scan (base_g, deg, dbin) -- 256 threads
//   blocks [49,49+GB): gemm1 (x fp32 @ wt1) -- threads 0..127 (waves 2,3 exit)
__global__ __launch_bounds__(256, 4) void sscan_gemm1_kernel(
    const unsigned* __restrict__ hist_g, unsigned short* __restrict__ base_g,
    int* __restrict__ deg, int* __restrict__ dbin,
    const float* __restrict__ A, const __half* __restrict__ Wt,
    const float* __restrict__ a_s, const float* __restrict__ a_d,
    __half* __restrict__ out, float* __restrict__ al_s, float* __restrict__ al_d) {
    __shared__ __align__(16) char smem[16640];
    const int tid = threadIdx.x;
    if (blockIdx.x < 49) {
        int* lbin = (int*)smem;
        int w = blockIdx.x * 256 + tid;
        lbin[tid] = 0;
        __syncthreads();
        if (w < NW) {
            unsigned r0 = 0, r1 = 0, r2 = 0, r3 = 0;
            for (int b = 0; b < NB; b++) {
                unsigned x = hist_g[(size_t)b * NW + w];
                uint2 st;
                st.x = r0 | (r1 << 16);
                st.y = r2 | (r3 << 16);
                *reinterpret_cast<uint2*>(&base_g[(size_t)b * NN + 4 * w]) = st;
                r0 += x & 0xffu; r1 += (x >> 8) & 0xffu; r2 += (x >> 16) & 0xffu; r3 += (x >> 24) & 0xffu;
            }
            uint4 dv; dv.x = r0; dv.y = r1; dv.z = r2; dv.w = r3;
            *reinterpret_cast<uint4*>(&deg[4 * w]) = dv;
            atomicAdd(&lbin[255 - (int)(r0 > 255u ? 255u : r0)], 1);
            atomicAdd(&lbin[255 - (int)(r1 > 255u ? 255u : r1)], 1);
            atomicAdd(&lbin[255 - (int)(r2 > 255u ? 255u : r2)], 1);
            atomicAdd(&lbin[255 - (int)(r3 > 255u ? 255u : r3)], 1);
        }
        __syncthreads();
        if (lbin[tid]) atomicAdd(&dbin[tid], lbin[tid]);
    } else {
        if (tid >= 128) return;    // waves 2,3 exit before any barrier
        gemm_body<128, float>(blockIdx.x - 49, tid, smem, A, Wt, a_s, a_d, out, al_s, al_d);
    }
}

// ------------------------------------------------------- 3-phase parallel scan
__global__ void scan1_kernel(const int* __restrict__ deg, int* bsum) {
    __shared__ int ws[4];
    int tid = threadIdx.x, lane = tid & 63, wid = tid >> 6;
    int i = blockIdx.x * 256 + tid;
    int v = (i < NN) ? deg[i] : 0;
    for (int o = 32; o >= 1; o >>= 1) v += __shfl_down(v, o, 64);
    if (lane == 0) ws[wid] = v;
    __syncthreads();
    if (tid == 0) bsum[blockIdx.x] = ws[0] + ws[1] + ws[2] + ws[3];
}

// block-sum prefix + 256-bin degree-histogram exclusive prefix (dpos)
__global__ void scan2_kernel(int* bsum, int* boff, const int* __restrict__ dbin,
                             int* __restrict__ dpos) {
    __shared__ int ws[4];
    int tid = threadIdx.x, lane = tid & 63, wid = tid >> 6;
    int v = (tid < 196) ? bsum[tid] : 0;
    int x = v;
    for (int o = 1; o < 64; o <<= 1) {
        int t = __shfl_up(x, o, 64);
        if (lane >= o) x += t;
    }
    if (lane == 63) ws[wid] = x;
    __syncthreads();
    if (tid == 0) {
        int acc = 0;
        for (int w = 0; w < 4; w++) { int t = ws[w]; ws[w] = acc; acc += t; }
    }
    __syncthreads();
    if (tid < 196) boff[tid] = x + ws[wid] - v;
    // ---- phase 2: degree-bin exclusive prefix (reuse ws after barrier)
    __syncthreads();
    int bv = dbin[tid];
    int bx = bv;
    for (int o = 1; o < 64; o <<= 1) {
        int t = __shfl_up(bx, o, 64);
        if (lane >= o) bx += t;
    }
    if (lane == 63) ws[wid] = bx;
    __syncthreads();
    if (tid == 0) {
        int acc = 0;
        for (int w = 0; w < 4; w++) { int t = ws[w]; ws[w] = acc; acc += t; }
    }
    __syncthreads();
    dpos[tid] = bx + ws[wid] - bv;
}

// scan3: node-offset scatter + LDS-aggregated counting-sort permutation
__global__ void scan3_kernel(const int* __restrict__ deg, const int* __restrict__ boff,
                             int* off, int* __restrict__ dpos, int* __restrict__ perm) {
    __shared__ int ws[4];
    __shared__ int lbin[256];    // per-block bin counts (LDS atomics)
    __shared__ int lbase[256];   // per-block reserved global base per bin
    int tid = threadIdx.x, lane = tid & 63, wid = tid >> 6;
    int i = blockIdx.x * 256 + tid;
    int v = (i < NN) ? deg[i] : 0;
    lbin[tid] = 0;
    int x = v;
    for (int o = 1; o < 64; o <<= 1) {
        int t = __shfl_up(x, o, 64);
        if (lane >= o) x += t;
    }
    if (lane == 63) ws[wid] = x;
    __syncthreads();
    if (tid == 0) {
        int acc = 0;
        for (int w = 0; w < 4; w++) { int t = ws[w]; ws[w] = acc; acc += t; }
    }
    __syncthreads();
    int incl = x + ws[wid] + boff[blockIdx.x];
    int bin = 255 - (v > 255 ? 255 : v);
    int rank = 0;
    if (i < NN) {
        off[i + 1] = incl;
        rank = atomicAdd(&lbin[bin], 1);     // fast LDS atomic
    }
    if (i == 0) off[0] = 0;
    __syncthreads();
    if (lbin[tid] > 0) lbase[tid] = atomicAdd(&dpos[tid], lbin[tid]);
    __syncthreads();
    if (i < NN) perm[lbase[bin] + rank] = i; // descending-degree schedule
}

// ---------------- rank via LDS + write packed edge record (no global atomics)
__global__ __launch_bounds__(256) void scatter_kernel(const int* __restrict__ ei,
                                                      const float* __restrict__ ea,
                                                      const unsigned short* __restrict__ base_g,
                                                      const int* __restrict__ soff,
                                                      uint4* __restrict__ erec) {
    __shared__ unsigned lc[NW];
    int b = blockIdx.x, tid = threadIdx.x;
    for (int w = tid; w < NW; w += 256) lc[w] = 0;
    __syncthreads();
    int e0 = b * EPB;
    const unsigned short* brow = base_g + (size_t)b * NN;
    for (int i = tid; i < EPB; i += 256) {
        int e = e0 + i;
        int d = ei[EE + e];
        int sh = (d & 3) * 8;
        unsigned old = atomicAdd(&lc[d >> 2], 1u << sh);
        int r = (int)((old >> sh) & 0xffu);
        int pos = soff[d] + (int)brow[d] + r;
        uint4 rec;
        rec.x = (unsigned)ei[e];
        rec.y = (unsigned)e;
        rec.z = __float_as_uint(ea[e]);
        rec.w = 0;
        erec[pos] = rec;
    }
}

// ---------------- standalone MFMA GEMM (layer 2): x12h fp16 @ wt2
template <int K, typename AT>
__global__ __launch_bounds__(128, 4) void gemm_kernel(const AT* __restrict__ A,
                                                      const __half* __restrict__ Wt,
                                                      const float* __restrict__ a_s,
                                                      const float* __restrict__ a_d,
                                                      __half* __restrict__ out,
                                                      float* __restrict__ al_s,
                                                      float* __restrict__ al_d) {
    __shared__ __align__(16) char smem[16640];
    gemm_body<K, AT>(blockIdx.x, threadIdx.x, smem, A, Wt, a_s, a_d, out, al_s, al_d);
}

// ------------- per-node (16 LANES per node, 16 nodes per 256-block, degree-
//               sorted schedule via perm): segment softmax (exp2-domain) +
//               weighted fp16 gather + bias/lrelu/LN -> fp16 x_out.
//               Per-group LDS strides padded (+8 banks); no barrier.
__global__ __launch_bounds__(256, 8) void aggregate_kernel(
    const int* __restrict__ perm,
    const int* __restrict__ soff, const uint4* __restrict__ erec,
    const __half* __restrict__ hfeat, const float* __restrict__ als,
    const float* __restrict__ al_d, const float* __restrict__ s_e,
    const float* __restrict__ bias, const float* __restrict__ g_ln,
    const float* __restrict__ b_ln,
    float* __restrict__ alpha_out, __half* __restrict__ x_out) {
    const int tid = threadIdx.x;
    const int grp = tid >> 4;          // node group 0..15 in block
    const int sl = tid & 15;           // sub-lane within group
    const int n = perm[blockIdx.x * 16 + grp];
    __shared__ float w_sh_all[16][WPAD];
    __shared__ int ioff_all[16][IPAD];  // byte offsets into hfeat (src*HC*2)
    float* w_sh = w_sh_all[grp];
    int* ioff_sh = ioff_all[grp];

    const int s0 = soff[n];
    const int deg = soff[n + 1] - s0;
    const int items = deg + 1;

    float adr[NH], ser[NH];
#pragma unroll
    for (int h = 0; h < NH; h++) { adr[h] = al_d[n * NH + h]; ser[h] = s_e[h]; }

    const int cA = sl * 4, cB = 64 + sl * 4, cC = 128 + sl * 2;
    const int hA = sl >> 3, hB = 2 + (sl >> 3);       // hC = 4
    float4 accA = make_float4(0.f, 0.f, 0.f, 0.f);
    float4 accB = make_float4(0.f, 0.f, 0.f, 0.f);
    float2 accC = make_float2(0.f, 0.f);

    if (items <= CH2) {
        // ---- pass A: logits into registers (2 tiles x 5 heads), per-head max, ea sum
        float rw[2][NH];
        float lm[NH];
#pragma unroll
        for (int h = 0; h < NH; h++) lm[h] = -3.0e38f;
        float eas = 0.f;
        int myy[2];
#pragma unroll
        for (int t = 0; t < 2; t++) {
            if (deg > 16 * t) {                  // group-uniform guard
                int i = sl + 16 * t;
                if (i < deg) {
                    uint4 rec = erec[s0 + i];
                    int src = (int)rec.x;
                    float eav = __uint_as_float(rec.z);
                    ioff_sh[i] = src * (HC * 2);
                    myy[t] = (int)rec.y;
                    eas += eav;
                    const float* ap = als + (size_t)src * ALS8;
                    float4 a4 = *reinterpret_cast<const float4*>(ap);
                    float a5 = ap[4];
                    float asv[5] = {a4.x, a4.y, a4.z, a4.w, a5};
#pragma unroll
                    for (int h = 0; h < NH; h++) {
                        float r = lrelu(asv[h] + adr[h] + eav * ser[h], 0.2f);
                        rw[t][h] = r;
                        lm[h] = fmaxf(lm[h], r);
                    }
                }
            }
        }
        // ---- 16-lane butterfly: max per head, sum of edge attrs
#pragma unroll
        for (int o = 1; o < 16; o <<= 1) {
#pragma unroll
            for (int h = 0; h < NH; h++) lm[h] = fmaxf(lm[h], __shfl_xor(lm[h], o, 64));
            eas += __shfl_xor(eas, o, 64);
        }
        float emean = eas / fmaxf((float)deg, 1.f);
        float m[NH], rs[NH];
        {
            const float* ap = als + (size_t)n * ALS8;
            float4 a4 = *reinterpret_cast<const float4*>(ap);
            float a5 = ap[4];
            float asv[5] = {a4.x, a4.y, a4.z, a4.w, a5};
#pragma unroll
            for (int h = 0; h < NH; h++) {
                rs[h] = lrelu(asv[h] + adr[h] + emean * ser[h], 0.2f);
                m[h] = fmaxf(lm[h], rs[h]);
            }
        }
        // ---- pass B: exp2 in registers + sum
        float ls[NH] = {0.f, 0.f, 0.f, 0.f, 0.f};
#pragma unroll
        for (int t = 0; t < 2; t++) {
            if (items > 16 * t) {
                int i = sl + 16 * t;
                if (i < deg) {
#pragma unroll
                    for (int h = 0; h < NH; h++) {
                        float w = exp2f(rw[t][h] - m[h]);
                        rw[t][h] = w;
                        ls[h] += w;
                    }
                } else if (i == deg) {           // self-loop owner lane
                    ioff_sh[i] = n * (HC * 2);
#pragma unroll
                    for (int h = 0; h < NH; h++) {
                        float w = exp2f(rs[h] - m[h]);
                        rw[t][h] = w;
                        ls[h] += w;
                    }
                }
            }
        }
#pragma unroll
        for (int o = 1; o < 16; o <<= 1) {
#pragma unroll
            for (int h = 0; h < NH; h++) ls[h] += __shfl_xor(ls[h], o, 64);
        }
        float dinv[NH];
#pragma unroll
        for (int h = 0; h < NH; h++) dinv[h] = 1.f / ls[h];
        // ---- normalize: final weights -> LDS + alpha writeback
#pragma unroll
        for (int t = 0; t < 2; t++) {
            if (items > 16 * t) {
                int i = sl + 16 * t;
                if (i < items) {
                    int opos = (i < deg) ? myy[t] : (EE + n);
#pragma unroll
                    for (int h = 0; h < NH; h++) {
                        float w = rw[t][h] * dinv[h];
                        w_sh[i * NH + h] = w;
                        alpha_out[(size_t)opos * NH + h] = w;
                    }
                }
            }
        }
        // (no barrier: w_sh/ioff_sh written+read by this wave only)
        // ---- pass C: 4-deep pipelined fp16 gather, 10 channels per lane
        const char* hb = (const char*)hfeat;
        for (int i0 = 0; i0 < items; i0 += 4) {
            float wA[4], wB[4], wC[4];
            uint2 vA[4], vB[4];
            unsigned vC[4];
#pragma unroll
            for (int j = 0; j < 4; j++) {
                int i = i0 + j;
                bool ok = i < items;
                int ii = ok ? i : 0;
                const char* rp = hb + (size_t)(unsigned)ioff_sh[ii];
                wA[j] = ok ? w_sh[ii * NH + hA] : 0.f;
                wB[j] = ok ? w_sh[ii * NH + hB] : 0.f;
                wC[j] = ok ? w_sh[ii * NH + 4] : 0.f;
                vA[j] = *reinterpret_cast<const uint2*>(rp + cA * 2);
                vB[j] = *reinterpret_cast<const uint2*>(rp + cB * 2);
                vC[j] = *reinterpret_cast<const unsigned*>(rp + cC * 2);
            }
#pragma unroll
            for (int j = 0; j < 4; j++) {
                float4 fA = h8_to_f4(vA[j]);
                accA.x += wA[j] * fA.x; accA.y += wA[j] * fA.y;
                accA.z += wA[j] * fA.z; accA.w += wA[j] * fA.w;
                float4 fB = h8_to_f4(vB[j]);
                accB.x += wB[j] * fB.x; accB.y += wB[j] * fB.y;
                accB.z += wB[j] * fB.z; accB.w += wB[j] * fB.w;
                __half2 pC = *reinterpret_cast<__half2*>(&vC[j]);
                accC.x += wC[j] * __low2float(pC);
                accC.y += wC[j] * __high2float(pC);
            }
        }
    } else {
        // ---- slow path (deg >= CH2): 16-lane streaming recompute, no LDS
        float lm[NH];
#pragma unroll
        for (int h = 0; h < NH; h++) lm[h] = -3.0e38f;
        float eas = 0.f;
        for (int i = sl; i < deg; i += 16) {
            uint4 rec = erec[s0 + i];
            int src = (int)rec.x;
            float eav = __uint_as_float(rec.z);
            eas += eav;
            const float* ap = als + (size_t)src * ALS8;
            float4 a4 = *reinterpret_cast<const float4*>(ap);
            float a5 = ap[4];
            float asv[5] = {a4.x, a4.y, a4.z, a4.w, a5};
#pragma unroll
            for (int h = 0; h < NH; h++) {
                float r = lrelu(asv[h] + adr[h] + eav * ser[h], 0.2f);
                lm[h] = fmaxf(lm[h], r);
            }
        }
#pragma unroll
        for (int o = 1; o < 16; o <<= 1) {
#pragma unroll
            for (int h = 0; h < NH; h++) lm[h] = fmaxf(lm[h], __shfl_xor(lm[h], o, 64));
            eas += __shfl_xor(eas, o, 64);
        }
        float emean = eas / fmaxf((float)deg, 1.f);
        float m[NH], rs[NH];
        {
            const float* ap = als + (size_t)n * ALS8;
#pragma unroll
            for (int h = 0; h < NH; h++) {
                rs[h] = lrelu(ap[h] + adr[h] + emean * ser[h], 0.2f);
                m[h] = fmaxf(lm[h], rs[h]);
            }
        }
        float ls[NH] = {0.f, 0.f, 0.f, 0.f, 0.f};
        for (int i = sl; i < items; i += 16) {
            int src; float eav;
            if (i < deg) { uint4 rec = erec[s0 + i]; src = (int)rec.x; eav = __uint_as_float(rec.z); }
            else         { src = n; eav = emean; }
            const float* ap = als + (size_t)src * ALS8;
#pragma unroll
            for (int h = 0; h < NH; h++) {
                float r = lrelu(ap[h] + adr[h] + eav * ser[h], 0.2f);
                ls[h] += exp2f(r - m[h]);
            }
        }
#pragma unroll
        for (int o = 1; o < 16; o <<= 1) {
#pragma unroll
            for (int h = 0; h < NH; h++) ls[h] += __shfl_xor(ls[h], o, 64);
        }
        float dinv[NH];
#pragma unroll
        for (int h = 0; h < NH; h++) dinv[h] = 1.f / ls[h];
        for (int i = sl; i < items; i += 16) {
            int src; float eav; int opos;
            if (i < deg) { uint4 rec = erec[s0 + i]; src = (int)rec.x; eav = __uint_as_float(rec.z); opos = (int)rec.y; }
            else         { src = n; eav = emean; opos = EE + n; }
            const float* ap = als + (size_t)src * ALS8;
#pragma unroll
            for (int h = 0; h < NH; h++) {
                float r = lrelu(ap[h] + adr[h] + eav * ser[h], 0.2f);
                alpha_out[(size_t)opos * NH + h] = exp2f(r - m[h]) * dinv[h];
            }
        }
        // serial gather over items; 16 lanes cover the 160 channels
        for (int i = 0; i < items; i++) {
            int src; float eav;
            if (i < deg) { uint4 rec = erec[s0 + i]; src = (int)rec.x; eav = __uint_as_float(rec.z); }
            else         { src = n; eav = emean; }
            const float* ap = als + (size_t)src * ALS8;
            float wAv = exp2f(lrelu(ap[hA] + adr[hA] + eav * ser[hA], 0.2f) - m[hA]) * dinv[hA];
            float wBv = exp2f(lrelu(ap[hB] + adr[hB] + eav * ser[hB], 0.2f) - m[hB]) * dinv[hB];
            float wCv = exp2f(lrelu(ap[4] + adr[4] + eav * ser[4], 0.2f) - m[4]) * dinv[4];
            const char* rp = (const char*)hfeat + (size_t)src * (HC * 2);
            uint2 vA = *reinterpret_cast<const uint2*>(rp + cA * 2);
            uint2 vB = *reinterpret_cast<const uint2*>(rp + cB * 2);
            unsigned vC = *reinterpret_cast<const unsigned*>(rp + cC * 2);
            float4 fA = h8_to_f4(vA);
            accA.x += wAv * fA.x; accA.y += wAv * fA.y;
            accA.z += wAv * fA.z; accA.w += wAv * fA.w;
            float4 fB = h8_to_f4(vB);
            accB.x += wBv * fB.x; accB.y += wBv * fB.y;
            accB.z += wBv * fB.z; accB.w += wBv * fB.w;
            __half2 pC = *reinterpret_cast<__half2*>(&vC);
            accC.x += wCv * __low2float(pC);
            accC.y += wCv * __high2float(pC);
        }
    }

    // ---- bias + lrelu + fused LayerNorm across 160 channels (16-lane butterfly)
    const float4 bA = *reinterpret_cast<const float4*>(&bias[cA]);
    const float4 bB = *reinterpret_cast<const float4*>(&bias[cB]);
    const float2 bC = *reinterpret_cast<const float2*>(&bias[cC]);
    float v0 = lrelu(accA.x + bA.x, 0.01f);
    float v1 = lrelu(accA.y + bA.y, 0.01f);
    float v2 = lrelu(accA.z + bA.z, 0.01f);
    float v3 = lrelu(accA.w + bA.w, 0.01f);
    float v4 = lrelu(accB.x + bB.x, 0.01f);
    float v5 = lrelu(accB.y + bB.y, 0.01f);
    float v6 = lrelu(accB.z + bB.z, 0.01f);
    float v7 = lrelu(accB.w + bB.w, 0.01f);
    float v8 = lrelu(accC.x + bC.x, 0.01f);
    float v9 = lrelu(accC.y + bC.y, 0.01f);
    float p1 = v0 + v1 + v2 + v3 + v4 + v5 + v6 + v7 + v8 + v9;
    float p2 = v0 * v0 + v1 * v1 + v2 * v2 + v3 * v3 + v4 * v4 +
               v5 * v5 + v6 * v6 + v7 * v7 + v8 * v8 + v9 * v9;
#pragma unroll
    for (int o = 1; o < 16; o <<= 1) {
        p1 += __shfl_xor(p1, o, 64);
        p2 += __shfl_xor(p2, o, 64);
    }
    float mean = p1 * (1.f / (float)HC);
    float var = p2 * (1.f / (float)HC) - mean * mean;
    float rstd = rsqrtf(var + 1e-5f);
    const float4 gA = *reinterpret_cast<const float4*>(&g_ln[cA]);
    const float4 gB = *reinterpret_cast<const float4*>(&g_ln[cB]);
    const float2 gC = *reinterpret_cast<const float2*>(&g_ln[cC]);
    const float4 tA = *reinterpret_cast<const float4*>(&b_ln[cA]);
    const float4 tB = *reinterpret_cast<const float4*>(&b_ln[cB]);
    const float2 tC = *reinterpret_cast<const float2*>(&b_ln[cC]);
    float o0 = (v0 - mean) * rstd * gA.x + tA.x;
    float o1 = (v1 - mean) * rstd * gA.y + tA.y;
    float o2 = (v2 - mean) * rstd * gA.z + tA.z;
    float o3 = (v3 - mean) * rstd * gA.w + tA.w;
    float o4 = (v4 - mean) * rstd * gB.x + tB.x;
    float o5 = (v5 - mean) * rstd * gB.y + tB.y;
    float o6 = (v6 - mean) * rstd * gB.z + tB.z;
    float o7 = (v7 - mean) * rstd * gB.w + tB.w;
    float o8 = (v8 - mean) * rstd * gC.x + tC.x;
    float o9 = (v9 - mean) * rstd * gC.y + tC.y;
    {
        __half2 hA01 = __floats2half2_rn(o0, o1);
        __half2 hA23 = __floats2half2_rn(o2, o3);
        uint2 stA;
        stA.x = *reinterpret_cast<unsigned*>(&hA01);
        stA.y = *reinterpret_cast<unsigned*>(&hA23);
        *reinterpret_cast<uint2*>(&x_out[(size_t)n * HC + cA]) = stA;
        __half2 hB01 = __floats2half2_rn(o4, o5);
        __half2 hB23 = __floats2half2_rn(o6, o7);
        uint2 stB;
        stB.x = *reinterpret_cast<unsigned*>(&hB01);
        stB.y = *reinterpret_cast<unsigned*>(&hB23);
        *reinterpret_cast<uint2*>(&x_out[(size_t)n * HC + cB]) = stB;
        __half2 hC = __floats2half2_rn(o8, o9);
        *reinterpret_cast<unsigned*>(&x_out[(size_t)n * HC + cC]) =
            *reinterpret_cast<unsigned*>(&hC);
    }
}

// -------- x3 = lrelu(x2 @ mw + mb) (MFMA, x2 fp16); direct fp32 store + pooled
__global__ __launch_bounds__(128, 4) void gemm3_kernel(const __half* __restrict__ A,
                                                       const __half* __restrict__ Wt,
                                                       const float* __restrict__ bias,
                                                       const int* __restrict__ batch,
                                                       float* __restrict__ x3,
                                                       float* __restrict__ psum) {
    __shared__ __align__(16) _Float16 Alds[32 * 40];
    __shared__ __align__(16) _Float16 Bt[160 * 40];
    __shared__ int bt[32];
    const int tid = threadIdx.x;
    const int w = tid >> 6, l = tid & 63;
    const int lr = l & 15, lq = l >> 4;
    const int base = blockIdx.x * 32;

    if (tid < 32) bt[tid] = batch[(base + tid < NN) ? (base + tid) : (NN - 1)];

    f32x4 acc[2][5];
#pragma unroll
    for (int mt = 0; mt < 2; mt++)
#pragma unroll
        for (int t = 0; t < 5; t++) acc[mt][t] = (f32x4){0.f, 0.f, 0.f, 0.f};

    for (int k0 = 0; k0 < HC; k0 += 32) {
        __syncthreads();
        {
            int row = tid >> 2, q = tid & 3;
            uint4 v = make_uint4(0, 0, 0, 0);
            if (base + row < NN)
                v = *reinterpret_cast<const uint4*>(&A[(size_t)(base + row) * HC + k0 + q * 8]);
            *reinterpret_cast<uint4*>(&Alds[row * 40 + q * 8]) = v;
        }
        for (int f = tid; f < 640; f += 128) {
            int c = f >> 2, q = f & 3;
            uint4 v = *reinterpret_cast<const uint4*>(&Wt[(size_t)c * HC + k0 + q * 8]);
            *reinterpret_cast<uint4*>(&Bt[c * 40 + q * 8]) = v;
        }
        __syncthreads();
        const f16x8 a0 = *reinterpret_cast<const f16x8*>(&Alds[lr * 40 + lq * 8]);
        const f16x8 a1 = *reinterpret_cast<const f16x8*>(&Alds[(16 + lr) * 40 + lq * 8]);
#pragma unroll
        for (int t = 0; t < 5; t++) {
            const f16x8 b = *reinterpret_cast<const f16x8*>(
                &Bt[((w * 5 + t) * 16 + lr) * 40 + lq * 8]);
            acc[0][t] = __builtin_amdgcn_mfma_f32_16x16x32_f16(a0, b, acc[0][t], 0, 0, 0);
            acc[1][t] = __builtin_amdgcn_mfma_f32_16x16x32_f16(a1, b, acc[1][t], 0, 0, 0);
        }
    }
    // ---- bias + lrelu, direct x3 store (quarter-coalesced), run-length pooled
#pragma unroll
    for (int t = 0; t < 5; t++) {
        int col = w * 80 + t * 16 + lr;
        float bj = bias[col];
        float run = 0.f;
        int g = bt[lq * 4];
#pragma unroll
        for (int mt = 0; mt < 2; mt++)
#pragma unroll
            for (int j = 0; j < 4; j++) {
                int row = mt * 16 + lq * 4 + j;
                bool ok = base + row < NN;
                float vv = lrelu(acc[mt][t][j] + bj, 0.01f);
                if (ok) x3[(size_t)(base + row) * HC + col] = vv;
                int gb = bt[row];
                if (gb != g) { atomicAdd(&psum[g * HC + col], run); run = 0.f; g = gb; }
                if (ok) run += vv;
            }
        atomicAdd(&psum[g * HC + col], run);
    }
}

__global__ void pooldiv_kernel(const float* __restrict__ psum, const int* __restrict__ gcnt,
                               float* pooled_out) {
    int i = blockIdx.x * 256 + threadIdx.x;
    if (i < NG * HC) pooled_out[i] = psum[i] / fmaxf((float)gcnt[i / HC], 1.f);
}

// ---------------------------------------------------------------------- launch
extern "C" void kernel_launch(void* const* d_in, const int* in_sizes, int n_in,
                              void* d_out, int out_size, void* d_ws, size_t ws_size,
                              hipStream_t stream) {
    const float* x    = (const float*)d_in[0];
    const int*   ei   = (const int*)d_in[1];
    const float* ea   = (const float*)d_in[2];
    const int*   batch= (const int*)d_in[3];
    const float* w1   = (const float*)d_in[4];
    const float* we1  = (const float*)d_in[5];
    const float* as1  = (const float*)d_in[6];
    const float* ad1  = (const float*)d_in[7];
    const float* ae1  = (const float*)d_in[8];
    const float* b1   = (const float*)d_in[9];
    const float* w2   = (const float*)d_in[10];
    const float* we2  = (const float*)d_in[11];
    const float* as2  = (const float*)d_in[12];
    const float* ad2  = (const float*)d_in[13];
    const float* ae2  = (const float*)d_in[14];
    const float* b2   = (const float*)d_in[15];
    const float* ln1g = (const float*)d_in[16];
    const float* ln1b = (const float*)d_in[17];
    const float* ln2g = (const float*)d_in[18];
    const float* ln2b = (const float*)d_in[19];
    const float* mw   = (const float*)d_in[20];
    const float* mb   = (const float*)d_in[21];

    float* out = (float*)d_out;
    float* pooled_out = out + (size_t)NN * HC;
    float* a1 = pooled_out + NG * HC;
    float* a2 = a1 + (size_t)(EE + NN) * NH;

    char* wp = (char*)d_ws;
    auto alloc = [&](size_t bytes) {
        void* p = (void*)wp;
        wp += (bytes + 255) & ~(size_t)255;
        return p;
    };
    // 40MB region, overlaid in time (hbuf now DISJOINT from base_g so gemm1
    // can run concurrently with sscan):
    //   hist_g [0..8)    dead after sscan
    //   base_g [8..24)   dead after scatter
    //   hbuf   [24..40)  written by gemm1 (no overlap with live hist_g/base_g)
    //   x12h   [0..16)   written by aggregate1 (hist_g dead; base_g dead)
    char* region = (char*)alloc(40 * 1024 * 1024);
    unsigned*       hist_g = (unsigned*)region;                   // 8 MB
    unsigned short* base_g = (unsigned short*)(region + 8 * 1024 * 1024); // 16 MB
    __half* hbuf = (__half*)(region + 24 * 1024 * 1024);          // 16 MB fp16 h
    __half* x12h = (__half*)region;                               // 16 MB fp16 x1/x2
    uint4* erec  = (uint4*)alloc((size_t)EE * 16);       // 12.8 MB
    float* als   = (float*)alloc((size_t)NN * ALS8 * 4); // padded al_s
    float* ald   = (float*)alloc((size_t)NN * NH * 4);
    int*   deg   = (int*)alloc((size_t)NN * 4);
    int*   soff  = (int*)alloc((size_t)(NN + 1) * 4);
    float* sbuf  = (float*)alloc(64);
    float* psum  = (float*)alloc((size_t)NG * HC * 4);
    int*   gcnt  = (int*)alloc((size_t)NG * 4);
    int*   bsum  = (int*)alloc(256 * 4);
    int*   boff  = (int*)alloc(256 * 4);
    int*   dbin  = (int*)alloc(256 * 4);
    int*   dpos  = (int*)alloc(256 * 4);
    int*   perm  = (int*)alloc((size_t)NN * 4);
    __half* wt1  = (__half*)alloc((size_t)160 * 128 * 2);  // W^T fp16 per layer
    __half* wt2  = (__half*)alloc((size_t)160 * 160 * 2);
    __half* wt3  = (__half*)alloc((size_t)160 * 160 * 2);

    const int GB = (NN + 31) / 32;   // 1563 gemm blocks

    // K1: prep | prepw | hist (independent)
    prep_fused_kernel<<<300, 256, 0, stream>>>(batch, psum, gcnt, we1, ae1, we2, ae2,
                                               sbuf, dbin, w1, w2, mw, wt1, wt2, wt3,
                                               ei, hist_g);
    // K2: sscan | gemm1 (independent after K1; disjoint memory)
    sscan_gemm1_kernel<<<49 + GB, 256, 0, stream>>>(hist_g, base_g, deg, dbin,
                                                    x, wt1, as1, ad1, hbuf, als, ald);
    scan1_kernel<<<196, 256, 0, stream>>>(deg, bsum);
    scan2_kernel<<<1, 256, 0, stream>>>(bsum, boff, dbin, dpos);
    scan3_kernel<<<196, 256, 0, stream>>>(deg, boff, soff, dpos, perm);
    scatter_kernel<<<NB, 256, 0, stream>>>(ei, ea, base_g, soff, erec);

    aggregate_kernel<<<3125, 256, 0, stream>>>(perm, soff, erec, hbuf, als, ald,
                                               sbuf, b1, ln1g, ln1b, a1, x12h);

    gemm_kernel<160, __half><<<GB, 128, 0, stream>>>(x12h, wt2, as2, ad2, hbuf, als, ald);
    aggregate_kernel<<<3125, 256, 0, stream>>>(perm, soff, erec, hbuf, als, ald,
                                               sbuf + 5, b2, ln2g, ln2b, a2, x12h);

    gemm3_kernel<<<GB, 128, 0, stream>>>(x12h, wt3, mb, batch, out, psum);
    pooldiv_kernel<<<40, 256, 0, stream>>>(psum, gcnt, pooled_out);
}